// Round 7
// baseline (305.199 us; speedup 1.0000x reference)
//
#include <hip/hip_runtime.h>
#include <math.h>

#define BS 4
#define NTOK 196
#define DCH 384
#define HD 6144
#define ROWS (BS*NTOK)          // 784
#define MPAD 896                // 7*128
#define SCALE 0.05103103630798287f  // 1/sqrt(384)

typedef unsigned short u16;
typedef __attribute__((ext_vector_type(8))) short bf8v;      // 8 bf16 (4 VGPR)
typedef __attribute__((ext_vector_type(4))) float f4v;
typedef __attribute__((ext_vector_type(16))) float f16v;
typedef __attribute__((ext_vector_type(8))) unsigned short u16x8;
typedef __attribute__((ext_vector_type(4))) unsigned short u16x4;

static __device__ __forceinline__ float b2f(u16 u) {
    unsigned int x = ((unsigned int)u) << 16;
    float f; __builtin_memcpy(&f, &x, 4); return f;
}
static __device__ __forceinline__ u16 f2b(float f) {
    unsigned int x; __builtin_memcpy(&x, &f, 4);
    unsigned int r = x + 0x7FFF + ((x >> 16) & 1);
    return (u16)(r >> 16);
}

// async global->LDS, 16B per lane; LDS dest must be wave-uniform base + lane*16 (linear)
static __device__ __forceinline__ void gload16(const u16* g, u16* l) {
    __builtin_amdgcn_global_load_lds(
        (const __attribute__((address_space(1))) unsigned int*)g,
        (__attribute__((address_space(3))) unsigned int*)l, 16, 0, 0);
}

// ---------------------------------------------------------------- LayerNorm (f32 + bf16 out, pad to 896)
__global__ __launch_bounds__(128) void ln_kernel(
    const float* __restrict__ x, const float* __restrict__ gamma,
    const float* __restrict__ beta, float* __restrict__ xn, u16* __restrict__ xnb)
{
    int row = blockIdx.x;
    int t = threadIdx.x;
    if (row >= ROWS) {
        xnb[(size_t)row*DCH + t] = 0;
        xnb[(size_t)row*DCH + t + 128] = 0;
        xnb[(size_t)row*DCH + t + 256] = 0;
        return;
    }
    const float* xr = x + (size_t)row * DCH;
    float v0 = xr[t], v1 = xr[t + 128], v2 = xr[t + 256];
    float s  = v0 + v1 + v2;
    float ss = v0*v0 + v1*v1 + v2*v2;
    #pragma unroll
    for (int off = 1; off < 64; off <<= 1) {
        s  += __shfl_xor(s,  off);
        ss += __shfl_xor(ss, off);
    }
    __shared__ float red[4];
    int wv = t >> 6;
    if ((t & 63) == 0) { red[wv*2] = s; red[wv*2+1] = ss; }
    __syncthreads();
    float S = red[0] + red[2], SS = red[1] + red[3];
    float mu  = S * (1.0f / DCH);
    float var = SS * (1.0f / DCH) - mu * mu;
    float inv = rsqrtf(var + 1e-5f);
    float* xo = xn + (size_t)row * DCH;
    u16*   xb = xnb + (size_t)row * DCH;
    float r0 = (v0 - mu) * inv * gamma[t]       + beta[t];
    float r1 = (v1 - mu) * inv * gamma[t + 128] + beta[t + 128];
    float r2 = (v2 - mu) * inv * gamma[t + 256] + beta[t + 256];
    xo[t] = r0; xo[t+128] = r1; xo[t+256] = r2;
    xb[t] = f2b(r0); xb[t+128] = f2b(r1); xb[t+256] = f2b(r2);
}

// ------------------------------------------------- W[384][6144] -> Wb[n][k] bf16 (k-contiguous)
__global__ __launch_bounds__(256) void convert_w_kernel(
    const float* __restrict__ Wq, const float* __restrict__ Wk, const float* __restrict__ Wv,
    u16* __restrict__ Wqb, u16* __restrict__ Wkb, u16* __restrict__ Wvb)
{
    const float* W = (blockIdx.z == 0) ? Wq : (blockIdx.z == 1) ? Wk : Wv;
    u16* Wb        = (blockIdx.z == 0) ? Wqb : (blockIdx.z == 1) ? Wkb : Wvb;
    __shared__ u16 tbuf[32][33];
    int tid = threadIdx.x;
    int k0 = blockIdx.y * 32, n0 = blockIdx.x * 32;
    #pragma unroll
    for (int it = 0; it < 4; it++) {
        int e = it*256 + tid; int kk = e >> 5, nn = e & 31;
        tbuf[kk][nn] = f2b(W[(size_t)(k0+kk)*HD + n0 + nn]);
    }
    __syncthreads();
    #pragma unroll
    for (int it = 0; it < 4; it++) {
        int e = it*256 + tid; int nn = e >> 5, kk = e & 31;
        Wb[(size_t)(n0+nn)*DCH + k0 + kk] = tbuf[kk][nn];
    }
}

// ------------------------------------------------- Wout[6144][384] -> Woutb[n][k] bf16, k=dc*16+h
__global__ __launch_bounds__(256) void convert_wout_kernel(
    const float* __restrict__ Wout, u16* __restrict__ Woutb)
{
    __shared__ u16 tbuf[128][65];
    int tid = threadIdx.x;
    int dc0 = blockIdx.x * 8;
    int n0  = blockIdx.y * 64;
    #pragma unroll
    for (int it = 0; it < 32; it++) {
        int e = it*256 + tid; int r = e >> 6, c = e & 63;
        int h = r >> 3, d = r & 7;
        tbuf[r][c] = f2b(Wout[(size_t)(h*DCH + dc0 + d)*DCH + n0 + c]);
    }
    __syncthreads();
    #pragma unroll
    for (int it = 0; it < 32; it++) {
        int e = it*256 + tid; int n = e >> 7, kk = e & 127;
        Woutb[(size_t)(n0+n)*HD + dc0*16 + kk] = tbuf[(kk & 15)*8 + (kk >> 4)][n];
    }
}

// ------------------------------------------------- MFMA proj GEMM -> q/k [bd][i][h], v [bd][h][j]
__global__ __launch_bounds__(256) void gemm_qkv(
    const u16* __restrict__ xnb,
    const u16* __restrict__ Wqb, const u16* __restrict__ Wkb, const u16* __restrict__ Wvb,
    u16* __restrict__ qt, u16* __restrict__ kt, u16* __restrict__ vt)
{
    const u16* Wb = (blockIdx.z == 0) ? Wqb : (blockIdx.z == 1) ? Wkb : Wvb;
    u16* C        = (blockIdx.z == 0) ? qt : (blockIdx.z == 1) ? kt : vt;
    __shared__ u16 As[128*64];
    __shared__ u16 Bs[128*64];
    int tid = threadIdx.x, lane = tid & 63, wv = tid >> 6;
    int wm = wv >> 1, wn = wv & 1;
    int row0 = blockIdx.y * 128, col0 = blockIdx.x * 128;
    f4v acc[4][4] = {};
    int srow = tid >> 3;                // 0..31 (row within each 32-row group)
    int g8 = tid & 7;                   // LDS chunk slot (linear dest)
    int gsrc = g8 ^ (srow & 7);         // pre-swizzled global source chunk (XOR involution)

    for (int k0 = 0; k0 < 384; k0 += 64) {
        __syncthreads();    // previous tile's reads done before overwrite
        #pragma unroll
        for (int c = 0; c < 4; c++) {
            int row = c*32 + srow;
            gload16(xnb + (size_t)(row0+row)*DCH + k0 + gsrc*8, &As[row*64 + g8*8]);
            gload16(Wb  + (size_t)(col0+row)*DCH + k0 + gsrc*8, &Bs[row*64 + g8*8]);
        }
        __syncthreads();    // vmcnt drained by barrier semantics
        #pragma unroll
        for (int ks = 0; ks < 2; ks++) {
            int gr = (ks*4 + (lane >> 4)) ^ (lane & 7);
            bf8v af[4], bf[4];
            #pragma unroll
            for (int m = 0; m < 4; m++)
                af[m] = *(const bf8v*)&As[(wm*64 + m*16 + (lane & 15))*64 + gr*8];
            #pragma unroll
            for (int n = 0; n < 4; n++)
                bf[n] = *(const bf8v*)&Bs[(wn*64 + n*16 + (lane & 15))*64 + gr*8];
            #pragma unroll
            for (int m = 0; m < 4; m++)
                #pragma unroll
                for (int n = 0; n < 4; n++)
                    acc[m][n] = __builtin_amdgcn_mfma_f32_16x16x32_bf16(af[m], bf[n], acc[m][n], 0, 0, 0);
        }
    }
    int cb = lane & 15, rg = lane >> 4;
    #pragma unroll
    for (int m = 0; m < 4; m++) {
        int r0 = row0 + wm*64 + m*16 + rg*4;
        if (r0 >= ROWS) continue;
        int b = r0 / NTOK, i = r0 - b*NTOK;
        #pragma unroll
        for (int n = 0; n < 4; n++) {
            int ncol = col0 + wn*64 + n*16 + cb;
            int h = ncol / DCH, dc = ncol - h*DCH;
            if (blockIdx.z == 2) {
                size_t addr = ((size_t)((b*DCH + dc)*16 + h))*NTOK + i;
                u16x4 o = {f2b(acc[m][n][0]), f2b(acc[m][n][1]), f2b(acc[m][n][2]), f2b(acc[m][n][3])};
                *(u16x4*)(C + addr) = o;
            } else {
                size_t a2 = ((size_t)(b*DCH + dc))*(NTOK*16) + (size_t)i*16 + h;
                C[a2]      = f2b(acc[m][n][0]);
                C[a2 + 16] = f2b(acc[m][n][1]);
                C[a2 + 32] = f2b(acc[m][n][2]);
                C[a2 + 48] = f2b(acc[m][n][3]);
            }
        }
    }
}

// ------------------------------------------------- MFMA attention: block = bd, wave = 32-row i-tile
// q/k: [bd][i][h] bf16; v: [bd][h][j] bf16; probs f32 (NT store); out bf16 [b,i][dc*16+h]
__global__ __launch_bounds__(448) void attn_kernel(
    const u16* __restrict__ qt, const u16* __restrict__ kt, const u16* __restrict__ vt,
    float* __restrict__ probs, u16* __restrict__ ot2)
{
    int bd = blockIdx.x;
    int b = bd / DCH, dc = bd - b*DCH;
    int tid = threadIdx.x;
    int it = tid >> 6;                 // 0..6 (wave = i-tile)
    int lane = tid & 63;
    int l31 = lane & 31, hi = lane >> 5;
    const u16* qb = qt + (size_t)bd * (NTOK*16);
    const u16* kb = kt + (size_t)bd * (NTOK*16);
    const u16* vb = vt + (size_t)bd * (NTOK*16);

    int iq = it*32 + l31;
    int iqc = iq < NTOK ? iq : NTOK-1;
    bf8v qf = *(const bf8v*)(qb + iqc*16 + hi*8);

    // QK^T swapped: S[jt] = K_jt @ Q  (row=j, col=i)
    f16v S[7];
    #pragma unroll
    for (int jt = 0; jt < 7; jt++) {
        int j = jt*32 + l31;
        int jc = j < NTOK ? j : NTOK-1;
        bf8v kf = *(const bf8v*)(kb + jc*16 + hi*8);
        f16v z = {};
        S[jt] = __builtin_amdgcn_mfma_f32_32x32x16_bf16(kf, qf, z, 0, 0, 0);
    }

    // row softmax: j(jt,r) = 32jt + 8(r>>2) + 4hi + (r&3)
    float m = -INFINITY;
    #pragma unroll
    for (int jt = 0; jt < 7; jt++) {
        #pragma unroll
        for (int r = 0; r < 16; r++) {
            bool act = (jt < 6) || (hi == 0 && r < 4);
            if (act) m = fmaxf(m, S[jt][r]);
        }
    }
    m = fmaxf(m, __shfl_xor(m, 32));
    m *= SCALE;
    float sum = 0.f;
    #pragma unroll
    for (int jt = 0; jt < 7; jt++) {
        #pragma unroll
        for (int r = 0; r < 16; r++) {
            bool act = (jt < 6) || (hi == 0 && r < 4);
            float pv = act ? __expf(S[jt][r] * SCALE - m) : 0.f;
            S[jt][r] = pv;
            sum += pv;
        }
    }
    sum += __shfl_xor(sum, 32);
    float inv = 1.0f / sum;
    #pragma unroll
    for (int jt = 0; jt < 7; jt++)
        #pragma unroll
        for (int r = 0; r < 16; r++)
            S[jt][r] *= inv;

    // write probs rows (NT ext-vector float4 stores; stream never re-read)
    if (iq < NTOK) {
        float* prow = probs + (size_t)bd * NTOK * NTOK + (size_t)iq * NTOK;
        #pragma unroll
        for (int jt = 0; jt < 7; jt++) {
            #pragma unroll
            for (int g = 0; g < 4; g++) {
                int joff = jt*32 + g*8 + hi*4;
                if (joff < NTOK) {
                    f4v o = {S[jt][4*g], S[jt][4*g+1], S[jt][4*g+2], S[jt][4*g+3]};
                    __builtin_nontemporal_store(o, (f4v*)(prow + joff));
                }
            }
        }
    }

    // PV: O[i][h'] += P_frag(jt,u) @ V_frag(jt,u); A row = i = l31
    f16v O = {};
    int vrow = (l31 & 15) * NTOK;
    #pragma unroll
    for (int jt = 0; jt < 7; jt++) {
        float pp_lo[4], pp_hi[4];
        #pragma unroll
        for (int e = 0; e < 4; e++) {
            pp_lo[e] = __shfl_xor(hi ? S[jt][e]    : S[jt][4+e],  32);
            pp_hi[e] = __shfl_xor(hi ? S[jt][8+e]  : S[jt][12+e], 32);
        }
        #pragma unroll
        for (int u = 0; u < 2; u++) {
            if (jt == 6 && u == 1) break;   // all-zero P
            u16 arr[8];
            #pragma unroll
            for (int e = 0; e < 4; e++) {
                float s03, s47;
                if (u == 0) {
                    s03 = hi ? pp_lo[e]     : S[jt][e];
                    s47 = hi ? S[jt][4+e]   : pp_lo[e];
                } else {
                    s03 = hi ? pp_hi[e]     : S[jt][8+e];
                    s47 = hi ? S[jt][12+e]  : pp_hi[e];
                }
                arr[e]   = f2b(s03);
                arr[4+e] = f2b(s47);
            }
            bf8v pf; __builtin_memcpy(&pf, arr, 16);
            int j0 = jt*32 + u*16 + hi*8;
            int off = vrow + j0;
            if (off > NTOK*16 - 8) off = NTOK*16 - 8;   // clamp (P=0 there)
            u16x4 vlo = *(const u16x4*)(vb + off);
            u16x4 vhi4 = *(const u16x4*)(vb + off + 4);
            u16 varr[8];
            #pragma unroll
            for (int e = 0; e < 4; e++) { varr[e] = vlo[e]; varr[4+e] = vhi4[e]; }
            bf8v vf; __builtin_memcpy(&vf, varr, 16);
            O = __builtin_amdgcn_mfma_f32_32x32x16_bf16(pf, vf, O, 0, 0, 0);
        }
    }

    // store: D row = i_local = (r&3)+8*(r>>2)+4*hi, col = h' = l31 (only <16)
    if (l31 < 16) {
        #pragma unroll
        for (int r = 0; r < 16; r++) {
            int i = it*32 + (r & 3) + 8*(r >> 2) + 4*hi;
            if (i < NTOK)
                ot2[((size_t)(b*NTOK + i))*HD + dc*16 + l31] = f2b(O[r]);
        }
    }
}

// ------------------------------------------------- MFMA out-proj, split-K
__global__ __launch_bounds__(256) void gemm_wout(
    const u16* __restrict__ A, const u16* __restrict__ Bw, float* __restrict__ partial)
{
    __shared__ u16 As[128*64];
    __shared__ u16 Bs[128*64];
    int tid = threadIdx.x, lane = tid & 63, wv = tid >> 6;
    int wm = wv >> 1, wn = wv & 1;
    int row0 = blockIdx.y * 128, col0 = blockIdx.x * 128;
    int kbase = blockIdx.z * 512;
    f4v acc[4][4] = {};
    int srow = tid >> 3;
    int g8 = tid & 7;
    int gsrc = g8 ^ (srow & 7);

    for (int k0 = kbase; k0 < kbase + 512; k0 += 64) {
        __syncthreads();
        #pragma unroll
        for (int c = 0; c < 4; c++) {
            int row = c*32 + srow;
            int arow = row0 + row; if (arow > ROWS-1) arow = ROWS-1;   // clamp (masked at store)
            gload16(A  + (size_t)arow*HD + k0 + gsrc*8, &As[row*64 + g8*8]);
            gload16(Bw + (size_t)(col0+row)*HD + k0 + gsrc*8, &Bs[row*64 + g8*8]);
        }
        __syncthreads();
        #pragma unroll
        for (int ks = 0; ks < 2; ks++) {
            int gr = (ks*4 + (lane >> 4)) ^ (lane & 7);
            bf8v af[4], bf[4];
            #pragma unroll
            for (int m = 0; m < 4; m++)
                af[m] = *(const bf8v*)&As[(wm*64 + m*16 + (lane & 15))*64 + gr*8];
            #pragma unroll
            for (int n = 0; n < 4; n++)
                bf[n] = *(const bf8v*)&Bs[(wn*64 + n*16 + (lane & 15))*64 + gr*8];
            #pragma unroll
            for (int m = 0; m < 4; m++)
                #pragma unroll
                for (int n = 0; n < 4; n++)
                    acc[m][n] = __builtin_amdgcn_mfma_f32_16x16x32_bf16(af[m], bf[n], acc[m][n], 0, 0, 0);
        }
    }
    float* P = partial + (size_t)blockIdx.z * ROWS * DCH;
    int cb = lane & 15, rg = lane >> 4;
    #pragma unroll
    for (int m = 0; m < 4; m++) {
        int r0 = row0 + wm*64 + m*16 + rg*4;
        #pragma unroll
        for (int n = 0; n < 4; n++) {
            int ncol = col0 + wn*64 + n*16 + cb;
            #pragma unroll
            for (int j = 0; j < 4; j++) {
                int r = r0 + j;
                if (r < ROWS) P[(size_t)r*DCH + ncol] = acc[m][n][j];
            }
        }
    }
}

// ------------------------------------------------- split-K reduce + residual
__global__ __launch_bounds__(256) void reduce_out_kernel(
    const float* __restrict__ partial, const float* __restrict__ xn, float* __restrict__ out)
{
    int e = blockIdx.x * 256 + threadIdx.x;
    if (e < ROWS * DCH) {
        float s = xn[e];
        #pragma unroll
        for (int c = 0; c < 12; c++)
            s += partial[(size_t)c * ROWS * DCH + e];
        out[e] = s;
    }
}

extern "C" void kernel_launch(void* const* d_in, const int* in_sizes, int n_in,
                              void* d_out, int out_size, void* d_ws, size_t ws_size,
                              hipStream_t stream) {
    (void)in_sizes; (void)n_in; (void)out_size; (void)ws_size;
    const float* x     = (const float*)d_in[0];
    const float* Wq    = (const float*)d_in[1];
    const float* Wk    = (const float*)d_in[2];
    const float* Wv    = (const float*)d_in[3];
    const float* Wout  = (const float*)d_in[4];
    const float* gamma = (const float*)d_in[5];
    const float* beta  = (const float*)d_in[6];

    float* out   = (float*)d_out;
    float* probs = out + (size_t)ROWS * DCH;

    char* w = (char*)d_ws;
    float* xn  = (float*)w;  w += (size_t)ROWS*DCH*4;
    u16* xnb   = (u16*)w;    w += (size_t)MPAD*DCH*2;
    u16* Wqb   = (u16*)w;    w += (size_t)HD*DCH*2;
    u16* Wkb   = (u16*)w;    w += (size_t)HD*DCH*2;
    u16* Wvb   = (u16*)w;    w += (size_t)HD*DCH*2;
    u16* Woutb = (u16*)w;    w += (size_t)DCH*HD*2;
    u16* qt    = (u16*)w;    w += (size_t)ROWS*HD*2;
    u16* kt    = (u16*)w;    w += (size_t)ROWS*HD*2;
    u16* vt    = (u16*)w;    w += (size_t)ROWS*HD*2;
    u16* ot2   = (u16*)w;    w += (size_t)ROWS*HD*2;
    float* partial = (float*)qt;   // q/k dead after attention

    hipLaunchKernelGGL(ln_kernel, dim3(MPAD), dim3(128), 0, stream, x, gamma, beta, xn, xnb);
    hipLaunchKernelGGL(convert_w_kernel, dim3(192, 12, 3), dim3(256), 0, stream,
                       Wq, Wk, Wv, Wqb, Wkb, Wvb);
    hipLaunchKernelGGL(convert_wout_kernel, dim3(48, 6), dim3(256), 0, stream, Wout, Woutb);
    hipLaunchKernelGGL(gemm_qkv, dim3(48, 7, 3), dim3(256), 0, stream,
                       xnb, Wqb, Wkb, Wvb, qt, kt, vt);
    hipLaunchKernelGGL(attn_kernel, dim3(BS * DCH), dim3(448), 0, stream,
                       qt, kt, vt, probs, ot2);
    hipLaunchKernelGGL(gemm_wout, dim3(3, 7, 12), dim3(256), 0, stream, ot2, Woutb, partial);
    hipLaunchKernelGGL(reduce_out_kernel, dim3((ROWS * DCH + 255) / 256), dim3(256), 0, stream,
                       partial, xn, out);
}

// Round 8
// 219.231 us; speedup vs baseline: 1.3921x; 1.3921x over previous
//
#include <hip/hip_runtime.h>
#include <math.h>

#define BS 4
#define NTOK 196
#define DCH 384
#define HD 6144
#define ROWS (BS*NTOK)          // 784
#define MPAD 896                // 7*128
#define SCALE 0.05103103630798287f  // 1/sqrt(384)

typedef unsigned short u16;
typedef __attribute__((ext_vector_type(8))) short bf8v;      // 8 bf16 (4 VGPR)
typedef __attribute__((ext_vector_type(4))) float f4v;
typedef __attribute__((ext_vector_type(16))) float f16v;
typedef __attribute__((ext_vector_type(8))) unsigned short u16x8;
typedef __attribute__((ext_vector_type(4))) unsigned short u16x4;

static __device__ __forceinline__ float b2f(u16 u) {
    unsigned int x = ((unsigned int)u) << 16;
    float f; __builtin_memcpy(&f, &x, 4); return f;
}
static __device__ __forceinline__ u16 f2b(float f) {
    unsigned int x; __builtin_memcpy(&x, &f, 4);
    unsigned int r = x + 0x7FFF + ((x >> 16) & 1);
    return (u16)(r >> 16);
}

// ---------------------------------------------------------------- LayerNorm (f32 + bf16 out, pad to 896)
__global__ __launch_bounds__(128) void ln_kernel(
    const float* __restrict__ x, const float* __restrict__ gamma,
    const float* __restrict__ beta, float* __restrict__ xn, u16* __restrict__ xnb)
{
    int row = blockIdx.x;
    int t = threadIdx.x;
    if (row >= ROWS) {
        xnb[(size_t)row*DCH + t] = 0;
        xnb[(size_t)row*DCH + t + 128] = 0;
        xnb[(size_t)row*DCH + t + 256] = 0;
        return;
    }
    const float* xr = x + (size_t)row * DCH;
    float v0 = xr[t], v1 = xr[t + 128], v2 = xr[t + 256];
    float s  = v0 + v1 + v2;
    float ss = v0*v0 + v1*v1 + v2*v2;
    #pragma unroll
    for (int off = 1; off < 64; off <<= 1) {
        s  += __shfl_xor(s,  off);
        ss += __shfl_xor(ss, off);
    }
    __shared__ float red[4];
    int wv = t >> 6;
    if ((t & 63) == 0) { red[wv*2] = s; red[wv*2+1] = ss; }
    __syncthreads();
    float S = red[0] + red[2], SS = red[1] + red[3];
    float mu  = S * (1.0f / DCH);
    float var = SS * (1.0f / DCH) - mu * mu;
    float inv = rsqrtf(var + 1e-5f);
    float* xo = xn + (size_t)row * DCH;
    u16*   xb = xnb + (size_t)row * DCH;
    float r0 = (v0 - mu) * inv * gamma[t]       + beta[t];
    float r1 = (v1 - mu) * inv * gamma[t + 128] + beta[t + 128];
    float r2 = (v2 - mu) * inv * gamma[t + 256] + beta[t + 256];
    xo[t] = r0; xo[t+128] = r1; xo[t+256] = r2;
    xb[t] = f2b(r0); xb[t+128] = f2b(r1); xb[t+256] = f2b(r2);
}

// ------------------------------------------------- W[384][6144] -> Wb[n][k] bf16 (k-contiguous)
__global__ __launch_bounds__(256) void convert_w_kernel(
    const float* __restrict__ Wq, const float* __restrict__ Wk, const float* __restrict__ Wv,
    u16* __restrict__ Wqb, u16* __restrict__ Wkb, u16* __restrict__ Wvb)
{
    const float* W = (blockIdx.z == 0) ? Wq : (blockIdx.z == 1) ? Wk : Wv;
    u16* Wb        = (blockIdx.z == 0) ? Wqb : (blockIdx.z == 1) ? Wkb : Wvb;
    __shared__ u16 tbuf[32][33];
    int tid = threadIdx.x;
    int k0 = blockIdx.y * 32, n0 = blockIdx.x * 32;
    #pragma unroll
    for (int it = 0; it < 4; it++) {
        int e = it*256 + tid; int kk = e >> 5, nn = e & 31;
        tbuf[kk][nn] = f2b(W[(size_t)(k0+kk)*HD + n0 + nn]);
    }
    __syncthreads();
    #pragma unroll
    for (int it = 0; it < 4; it++) {
        int e = it*256 + tid; int nn = e >> 5, kk = e & 31;
        Wb[(size_t)(n0+nn)*DCH + k0 + kk] = tbuf[kk][nn];
    }
}

// ------------------------------------------------- Wout[6144][384] -> Woutb[n][k] bf16, k=dc*16+h
__global__ __launch_bounds__(256) void convert_wout_kernel(
    const float* __restrict__ Wout, u16* __restrict__ Woutb)
{
    __shared__ u16 tbuf[128][65];
    int tid = threadIdx.x;
    int dc0 = blockIdx.x * 8;
    int n0  = blockIdx.y * 64;
    #pragma unroll
    for (int it = 0; it < 32; it++) {
        int e = it*256 + tid; int r = e >> 6, c = e & 63;
        int h = r >> 3, d = r & 7;
        tbuf[r][c] = f2b(Wout[(size_t)(h*DCH + dc0 + d)*DCH + n0 + c]);
    }
    __syncthreads();
    #pragma unroll
    for (int it = 0; it < 32; it++) {
        int e = it*256 + tid; int n = e >> 7, kk = e & 127;
        Woutb[(size_t)(n0+n)*HD + dc0*16 + kk] = tbuf[(kk & 15)*8 + (kk >> 4)][n];
    }
}

// ------------------------------------------------- MFMA proj GEMM (reg-staged) -> q/k [bd][i][h], v [bd][h][j]
__global__ __launch_bounds__(256) void gemm_qkv(
    const u16* __restrict__ xnb,
    const u16* __restrict__ Wqb, const u16* __restrict__ Wkb, const u16* __restrict__ Wvb,
    u16* __restrict__ qt, u16* __restrict__ kt, u16* __restrict__ vt)
{
    const u16* Wb = (blockIdx.z == 0) ? Wqb : (blockIdx.z == 1) ? Wkb : Wvb;
    u16* C        = (blockIdx.z == 0) ? qt : (blockIdx.z == 1) ? kt : vt;
    __shared__ u16 As[128*64];
    __shared__ u16 Bs[128*64];
    int tid = threadIdx.x, lane = tid & 63, wv = tid >> 6;
    int wm = wv >> 1, wn = wv & 1;
    int row0 = blockIdx.y * 128, col0 = blockIdx.x * 128;
    f4v acc[4][4] = {};
    int rsub = tid >> 3;
    int g8 = tid & 7;
    int g8s = g8 ^ (rsub & 7);

    for (int k0 = 0; k0 < 384; k0 += 64) {
        u16x8 ra[4], rb[4];
        #pragma unroll
        for (int c = 0; c < 4; c++) {
            int row = c*32 + rsub;
            ra[c] = *(const u16x8*)(xnb + (size_t)(row0+row)*DCH + k0 + g8*8);
            rb[c] = *(const u16x8*)(Wb  + (size_t)(col0+row)*DCH + k0 + g8*8);
        }
        __syncthreads();
        #pragma unroll
        for (int c = 0; c < 4; c++) {
            int row = c*32 + rsub;
            *(u16x8*)&As[row*64 + g8s*8] = ra[c];
            *(u16x8*)&Bs[row*64 + g8s*8] = rb[c];
        }
        __syncthreads();
        #pragma unroll
        for (int ks = 0; ks < 2; ks++) {
            int gr = (ks*4 + (lane >> 4)) ^ (lane & 7);
            bf8v af[4], bf[4];
            #pragma unroll
            for (int m = 0; m < 4; m++)
                af[m] = *(const bf8v*)&As[(wm*64 + m*16 + (lane & 15))*64 + gr*8];
            #pragma unroll
            for (int n = 0; n < 4; n++)
                bf[n] = *(const bf8v*)&Bs[(wn*64 + n*16 + (lane & 15))*64 + gr*8];
            #pragma unroll
            for (int m = 0; m < 4; m++)
                #pragma unroll
                for (int n = 0; n < 4; n++)
                    acc[m][n] = __builtin_amdgcn_mfma_f32_16x16x32_bf16(af[m], bf[n], acc[m][n], 0, 0, 0);
        }
    }
    int cb = lane & 15, rg = lane >> 4;
    #pragma unroll
    for (int m = 0; m < 4; m++) {
        int r0 = row0 + wm*64 + m*16 + rg*4;
        if (r0 >= ROWS) continue;
        int b = r0 / NTOK, i = r0 - b*NTOK;
        #pragma unroll
        for (int n = 0; n < 4; n++) {
            int ncol = col0 + wn*64 + n*16 + cb;
            int h = ncol / DCH, dc = ncol - h*DCH;
            if (blockIdx.z == 2) {
                size_t addr = ((size_t)((b*DCH + dc)*16 + h))*NTOK + i;
                u16x4 o = {f2b(acc[m][n][0]), f2b(acc[m][n][1]), f2b(acc[m][n][2]), f2b(acc[m][n][3])};
                *(u16x4*)(C + addr) = o;
            } else {
                size_t a2 = ((size_t)(b*DCH + dc))*(NTOK*16) + (size_t)i*16 + h;
                C[a2]      = f2b(acc[m][n][0]);
                C[a2 + 16] = f2b(acc[m][n][1]);
                C[a2 + 32] = f2b(acc[m][n][2]);
                C[a2 + 48] = f2b(acc[m][n][3]);
            }
        }
    }
}

// ------------------------------------------------- MFMA attention, two-pass online softmax
// block = (bd, i-tile), 64 threads (1 wave). q/k: [bd][i][h]; v: [bd][h][j]; probs f32; out bf16 [b,i][dc*16+h]
__global__ __launch_bounds__(64) void attn_kernel(
    const u16* __restrict__ qt, const u16* __restrict__ kt, const u16* __restrict__ vt,
    float* __restrict__ probs, u16* __restrict__ ot2)
{
    int bx = blockIdx.x;
    int bd = bx / 7, it = bx - bd*7;
    int b = bd / DCH, dc = bd - b*DCH;
    int lane = threadIdx.x;
    int l31 = lane & 31, hi = lane >> 5;
    const u16* qb = qt + (size_t)bd * (NTOK*16);
    const u16* kb = kt + (size_t)bd * (NTOK*16);
    const u16* vb = vt + (size_t)bd * (NTOK*16);

    int iq = it*32 + l31;
    int iqc = iq < NTOK ? iq : NTOK-1;
    bf8v qf = *(const bf8v*)(qb + iqc*16 + hi*8);

    // ---- pass 1: online (max, sum) over scaled scores; S discarded per tile
    float M = -INFINITY, Sig = 0.f;
    #pragma unroll
    for (int jt = 0; jt < 7; jt++) {
        int j = jt*32 + l31;
        int jc = j < NTOK ? j : NTOK-1;
        bf8v kf = *(const bf8v*)(kb + jc*16 + hi*8);
        f16v z = {};
        f16v Sv = __builtin_amdgcn_mfma_f32_32x32x16_bf16(kf, qf, z, 0, 0, 0);
        float a[16];
        #pragma unroll
        for (int r = 0; r < 16; r++) {
            bool act = (jt < 6) || (hi == 0 && r < 4);
            a[r] = act ? Sv[r] * SCALE : -INFINITY;
        }
        // tree max
        #pragma unroll
        for (int st = 8; st >= 1; st >>= 1)
            #pragma unroll
            for (int r = 0; r < 16; r++)
                if (r < st) a[r] = fmaxf(a[r], a[r + st]);
        float nm = fmaxf(M, a[0]);
        float e[16];
        #pragma unroll
        for (int r = 0; r < 16; r++) {
            bool act = (jt < 6) || (hi == 0 && r < 4);
            e[r] = act ? __expf(Sv[r] * SCALE - nm) : 0.f;
        }
        #pragma unroll
        for (int st = 8; st >= 1; st >>= 1)
            #pragma unroll
            for (int r = 0; r < 16; r++)
                if (r < st) e[r] += e[r + st];
        Sig = Sig * __expf(M - nm) + e[0];
        M = nm;
    }
    // merge with partner lane (other half of the row)
    {
        float Mo = __shfl_xor(M, 32);
        float So = __shfl_xor(Sig, 32);
        float Mg = fmaxf(M, Mo);
        Sig = Sig * __expf(M - Mg) + So * __expf(Mo - Mg);
        M = Mg;
    }
    float inv = 1.0f / Sig;

    float* prow = probs + (size_t)bd * NTOK * NTOK + (size_t)iq * NTOK;

    // ---- pass 2: recompute tiles, normalize, write probs, PV
    f16v O = {};
    int vrow = (l31 & 15) * NTOK;
    #pragma unroll
    for (int jt = 0; jt < 7; jt++) {
        int j = jt*32 + l31;
        int jc = j < NTOK ? j : NTOK-1;
        bf8v kf = *(const bf8v*)(kb + jc*16 + hi*8);
        f16v z = {};
        f16v Sv = __builtin_amdgcn_mfma_f32_32x32x16_bf16(kf, qf, z, 0, 0, 0);
        float p[16];
        #pragma unroll
        for (int r = 0; r < 16; r++) {
            bool act = (jt < 6) || (hi == 0 && r < 4);
            p[r] = act ? __expf(Sv[r] * SCALE - M) * inv : 0.f;
        }
        if (iq < NTOK) {
            #pragma unroll
            for (int g = 0; g < 4; g++) {
                int joff = jt*32 + g*8 + hi*4;
                if (joff < NTOK) {
                    f4v o = {p[4*g], p[4*g+1], p[4*g+2], p[4*g+3]};
                    *(f4v*)(prow + joff) = o;
                }
            }
        }
        float pp_lo[4], pp_hi[4];
        #pragma unroll
        for (int e = 0; e < 4; e++) {
            pp_lo[e] = __shfl_xor(hi ? p[e]    : p[4+e],  32);
            pp_hi[e] = __shfl_xor(hi ? p[8+e]  : p[12+e], 32);
        }
        #pragma unroll
        for (int u = 0; u < 2; u++) {
            if (jt == 6 && u == 1) break;   // all-zero P
            u16 arr[8];
            #pragma unroll
            for (int e = 0; e < 4; e++) {
                float s03, s47;
                if (u == 0) {
                    s03 = hi ? pp_lo[e]   : p[e];
                    s47 = hi ? p[4+e]     : pp_lo[e];
                } else {
                    s03 = hi ? pp_hi[e]   : p[8+e];
                    s47 = hi ? p[12+e]    : pp_hi[e];
                }
                arr[e]   = f2b(s03);
                arr[4+e] = f2b(s47);
            }
            bf8v pf; __builtin_memcpy(&pf, arr, 16);
            int j0 = jt*32 + u*16 + hi*8;
            int off = vrow + j0;
            if (off > NTOK*16 - 8) off = NTOK*16 - 8;   // clamp (P=0 there)
            u16x4 vlo = *(const u16x4*)(vb + off);
            u16x4 vhi4 = *(const u16x4*)(vb + off + 4);
            u16 varr[8];
            #pragma unroll
            for (int e = 0; e < 4; e++) { varr[e] = vlo[e]; varr[4+e] = vhi4[e]; }
            bf8v vf; __builtin_memcpy(&vf, varr, 16);
            O = __builtin_amdgcn_mfma_f32_32x32x16_bf16(pf, vf, O, 0, 0, 0);
        }
    }

    // store: D row = i_local = (r&3)+8*(r>>2)+4*hi, col = h' = l31 (only <16)
    if (l31 < 16) {
        #pragma unroll
        for (int r = 0; r < 16; r++) {
            int i = it*32 + (r & 3) + 8*(r >> 2) + 4*hi;
            if (i < NTOK)
                ot2[((size_t)(b*NTOK + i))*HD + dc*16 + l31] = f2b(O[r]);
        }
    }
}

// ------------------------------------------------- MFMA out-proj (reg-staged), split-K
__global__ __launch_bounds__(256) void gemm_wout(
    const u16* __restrict__ A, const u16* __restrict__ Bw, float* __restrict__ partial)
{
    __shared__ u16 As[128*64];
    __shared__ u16 Bs[128*64];
    int tid = threadIdx.x, lane = tid & 63, wv = tid >> 6;
    int wm = wv >> 1, wn = wv & 1;
    int row0 = blockIdx.y * 128, col0 = blockIdx.x * 128;
    int kbase = blockIdx.z * 512;
    f4v acc[4][4] = {};
    int rsub = tid >> 3;
    int g8 = tid & 7;
    int g8s = g8 ^ (rsub & 7);

    for (int k0 = kbase; k0 < kbase + 512; k0 += 64) {
        u16x8 ra[4], rb[4];
        #pragma unroll
        for (int c = 0; c < 4; c++) {
            int row = c*32 + rsub;
            int arow = row0 + row; if (arow > ROWS-1) arow = ROWS-1;   // clamp (masked at store)
            ra[c] = *(const u16x8*)(A  + (size_t)arow*HD + k0 + g8*8);
            rb[c] = *(const u16x8*)(Bw + (size_t)(col0+row)*HD + k0 + g8*8);
        }
        __syncthreads();
        #pragma unroll
        for (int c = 0; c < 4; c++) {
            int row = c*32 + rsub;
            *(u16x8*)&As[row*64 + g8s*8] = ra[c];
            *(u16x8*)&Bs[row*64 + g8s*8] = rb[c];
        }
        __syncthreads();
        #pragma unroll
        for (int ks = 0; ks < 2; ks++) {
            int gr = (ks*4 + (lane >> 4)) ^ (lane & 7);
            bf8v af[4], bf[4];
            #pragma unroll
            for (int m = 0; m < 4; m++)
                af[m] = *(const bf8v*)&As[(wm*64 + m*16 + (lane & 15))*64 + gr*8];
            #pragma unroll
            for (int n = 0; n < 4; n++)
                bf[n] = *(const bf8v*)&Bs[(wn*64 + n*16 + (lane & 15))*64 + gr*8];
            #pragma unroll
            for (int m = 0; m < 4; m++)
                #pragma unroll
                for (int n = 0; n < 4; n++)
                    acc[m][n] = __builtin_amdgcn_mfma_f32_16x16x32_bf16(af[m], bf[n], acc[m][n], 0, 0, 0);
        }
    }
    float* P = partial + (size_t)blockIdx.z * ROWS * DCH;
    int cb = lane & 15, rg = lane >> 4;
    #pragma unroll
    for (int m = 0; m < 4; m++) {
        int r0 = row0 + wm*64 + m*16 + rg*4;
        #pragma unroll
        for (int n = 0; n < 4; n++) {
            int ncol = col0 + wn*64 + n*16 + cb;
            #pragma unroll
            for (int j = 0; j < 4; j++) {
                int r = r0 + j;
                if (r < ROWS) P[(size_t)r*DCH + ncol] = acc[m][n][j];
            }
        }
    }
}

// ------------------------------------------------- split-K reduce + residual
__global__ __launch_bounds__(256) void reduce_out_kernel(
    const float* __restrict__ partial, const float* __restrict__ xn, float* __restrict__ out)
{
    int e = blockIdx.x * 256 + threadIdx.x;
    if (e < ROWS * DCH) {
        float s = xn[e];
        #pragma unroll
        for (int c = 0; c < 12; c++)
            s += partial[(size_t)c * ROWS * DCH + e];
        out[e] = s;
    }
}

extern "C" void kernel_launch(void* const* d_in, const int* in_sizes, int n_in,
                              void* d_out, int out_size, void* d_ws, size_t ws_size,
                              hipStream_t stream) {
    (void)in_sizes; (void)n_in; (void)out_size; (void)ws_size;
    const float* x     = (const float*)d_in[0];
    const float* Wq    = (const float*)d_in[1];
    const float* Wk    = (const float*)d_in[2];
    const float* Wv    = (const float*)d_in[3];
    const float* Wout  = (const float*)d_in[4];
    const float* gamma = (const float*)d_in[5];
    const float* beta  = (const float*)d_in[6];

    float* out   = (float*)d_out;
    float* probs = out + (size_t)ROWS * DCH;

    char* w = (char*)d_ws;
    float* xn  = (float*)w;  w += (size_t)ROWS*DCH*4;
    u16* xnb   = (u16*)w;    w += (size_t)MPAD*DCH*2;
    u16* Wqb   = (u16*)w;    w += (size_t)HD*DCH*2;
    u16* Wkb   = (u16*)w;    w += (size_t)HD*DCH*2;
    u16* Wvb   = (u16*)w;    w += (size_t)HD*DCH*2;
    u16* Woutb = (u16*)w;    w += (size_t)DCH*HD*2;
    u16* qt    = (u16*)w;    w += (size_t)ROWS*HD*2;
    u16* kt    = (u16*)w;    w += (size_t)ROWS*HD*2;
    u16* vt    = (u16*)w;    w += (size_t)ROWS*HD*2;
    u16* ot2   = (u16*)w;    w += (size_t)ROWS*HD*2;
    float* partial = (float*)qt;   // q/k dead after attention

    hipLaunchKernelGGL(ln_kernel, dim3(MPAD), dim3(128), 0, stream, x, gamma, beta, xn, xnb);
    hipLaunchKernelGGL(convert_w_kernel, dim3(192, 12, 3), dim3(256), 0, stream,
                       Wq, Wk, Wv, Wqb, Wkb, Wvb);
    hipLaunchKernelGGL(convert_wout_kernel, dim3(48, 6), dim3(256), 0, stream, Wout, Woutb);
    hipLaunchKernelGGL(gemm_qkv, dim3(48, 7, 3), dim3(256), 0, stream,
                       xnb, Wqb, Wkb, Wvb, qt, kt, vt);
    hipLaunchKernelGGL(attn_kernel, dim3(BS * DCH * 7), dim3(64), 0, stream,
                       qt, kt, vt, probs, ot2);
    hipLaunchKernelGGL(gemm_wout, dim3(3, 7, 12), dim3(256), 0, stream, ot2, Woutb, partial);
    hipLaunchKernelGGL(reduce_out_kernel, dim3((ROWS * DCH + 255) / 256), dim3(256), 0, stream,
                       partial, xn, out);
}

// Round 9
// 180.239 us; speedup vs baseline: 1.6933x; 1.2163x over previous
//
#include <hip/hip_runtime.h>
#include <math.h>

#define BS 4
#define NTOK 196
#define DCH 384
#define HD 6144
#define ROWS (BS*NTOK)          // 784
#define MPAD 896                // 7*128
#define SCALE 0.05103103630798287f  // 1/sqrt(384)

typedef unsigned short u16;
typedef __attribute__((ext_vector_type(8))) short bf8v;      // 8 bf16 (4 VGPR)
typedef __attribute__((ext_vector_type(4))) float f4v;
typedef __attribute__((ext_vector_type(16))) float f16v;
typedef __attribute__((ext_vector_type(8))) unsigned short u16x8;
typedef __attribute__((ext_vector_type(4))) unsigned short u16x4;
typedef __attribute__((ext_vector_type(2))) unsigned int u32x2;

static __device__ __forceinline__ float b2f(u16 u) {
    unsigned int x = ((unsigned int)u) << 16;
    float f; __builtin_memcpy(&f, &x, 4); return f;
}
static __device__ __forceinline__ u16 f2b(float f) {
    unsigned int x; __builtin_memcpy(&x, &f, 4);
    unsigned int r = x + 0x7FFF + ((x >> 16) & 1);
    return (u16)(r >> 16);
}
static __device__ __forceinline__ unsigned int pack2(float lo, float hi) {
    unsigned int r;
    asm("v_cvt_pk_bf16_f32 %0, %1, %2" : "=v"(r) : "v"(lo), "v"(hi));
    return r;
}
static __device__ __forceinline__ float blo(unsigned int u) {
    unsigned int x = u << 16; float f; __builtin_memcpy(&f, &x, 4); return f;
}
static __device__ __forceinline__ float bhi(unsigned int u) {
    unsigned int x = u & 0xffff0000u; float f; __builtin_memcpy(&f, &x, 4); return f;
}

// ---------------------------------------------------------------- LayerNorm (f32 + bf16 out, pad to 896)
__global__ __launch_bounds__(128) void ln_kernel(
    const float* __restrict__ x, const float* __restrict__ gamma,
    const float* __restrict__ beta, float* __restrict__ xn, u16* __restrict__ xnb)
{
    int row = blockIdx.x;
    int t = threadIdx.x;
    if (row >= ROWS) {
        xnb[(size_t)row*DCH + t] = 0;
        xnb[(size_t)row*DCH + t + 128] = 0;
        xnb[(size_t)row*DCH + t + 256] = 0;
        return;
    }
    const float* xr = x + (size_t)row * DCH;
    float v0 = xr[t], v1 = xr[t + 128], v2 = xr[t + 256];
    float s  = v0 + v1 + v2;
    float ss = v0*v0 + v1*v1 + v2*v2;
    #pragma unroll
    for (int off = 1; off < 64; off <<= 1) {
        s  += __shfl_xor(s,  off);
        ss += __shfl_xor(ss, off);
    }
    __shared__ float red[4];
    int wv = t >> 6;
    if ((t & 63) == 0) { red[wv*2] = s; red[wv*2+1] = ss; }
    __syncthreads();
    float S = red[0] + red[2], SS = red[1] + red[3];
    float mu  = S * (1.0f / DCH);
    float var = SS * (1.0f / DCH) - mu * mu;
    float inv = rsqrtf(var + 1e-5f);
    float* xo = xn + (size_t)row * DCH;
    u16*   xb = xnb + (size_t)row * DCH;
    float r0 = (v0 - mu) * inv * gamma[t]       + beta[t];
    float r1 = (v1 - mu) * inv * gamma[t + 128] + beta[t + 128];
    float r2 = (v2 - mu) * inv * gamma[t + 256] + beta[t + 256];
    xo[t] = r0; xo[t+128] = r1; xo[t+256] = r2;
    xb[t] = f2b(r0); xb[t+128] = f2b(r1); xb[t+256] = f2b(r2);
}

// ------------------------------------------------- W[384][6144] -> Wb[n][k] bf16 (k-contiguous)
__global__ __launch_bounds__(256) void convert_w_kernel(
    const float* __restrict__ Wq, const float* __restrict__ Wk, const float* __restrict__ Wv,
    u16* __restrict__ Wqb, u16* __restrict__ Wkb, u16* __restrict__ Wvb)
{
    const float* W = (blockIdx.z == 0) ? Wq : (blockIdx.z == 1) ? Wk : Wv;
    u16* Wb        = (blockIdx.z == 0) ? Wqb : (blockIdx.z == 1) ? Wkb : Wvb;
    __shared__ u16 tbuf[32][33];
    int tid = threadIdx.x;
    int k0 = blockIdx.y * 32, n0 = blockIdx.x * 32;
    #pragma unroll
    for (int it = 0; it < 4; it++) {
        int e = it*256 + tid; int kk = e >> 5, nn = e & 31;
        tbuf[kk][nn] = f2b(W[(size_t)(k0+kk)*HD + n0 + nn]);
    }
    __syncthreads();
    #pragma unroll
    for (int it = 0; it < 4; it++) {
        int e = it*256 + tid; int nn = e >> 5, kk = e & 31;
        Wb[(size_t)(n0+nn)*DCH + k0 + kk] = tbuf[kk][nn];
    }
}

// ------------------------------------------------- Wout[6144][384] -> Woutb[n][k] bf16, k=dc*16+h
__global__ __launch_bounds__(256) void convert_wout_kernel(
    const float* __restrict__ Wout, u16* __restrict__ Woutb)
{
    __shared__ u16 tbuf[128][65];
    int tid = threadIdx.x;
    int dc0 = blockIdx.x * 8;
    int n0  = blockIdx.y * 64;
    #pragma unroll
    for (int it = 0; it < 32; it++) {
        int e = it*256 + tid; int r = e >> 6, c = e & 63;
        int h = r >> 3, d = r & 7;
        tbuf[r][c] = f2b(Wout[(size_t)(h*DCH + dc0 + d)*DCH + n0 + c]);
    }
    __syncthreads();
    #pragma unroll
    for (int it = 0; it < 32; it++) {
        int e = it*256 + tid; int n = e >> 7, kk = e & 127;
        Woutb[(size_t)(n0+n)*HD + dc0*16 + kk] = tbuf[(kk & 15)*8 + (kk >> 4)][n];
    }
}

// ------------------------------------------------- MFMA proj GEMM (reg-staged) -> q/k [bd][i][h], v [bd][h][j]
__global__ __launch_bounds__(256) void gemm_qkv(
    const u16* __restrict__ xnb,
    const u16* __restrict__ Wqb, const u16* __restrict__ Wkb, const u16* __restrict__ Wvb,
    u16* __restrict__ qt, u16* __restrict__ kt, u16* __restrict__ vt)
{
    const u16* Wb = (blockIdx.z == 0) ? Wqb : (blockIdx.z == 1) ? Wkb : Wvb;
    u16* C        = (blockIdx.z == 0) ? qt : (blockIdx.z == 1) ? kt : vt;
    __shared__ u16 As[128*64];
    __shared__ u16 Bs[128*64];
    int tid = threadIdx.x, lane = tid & 63, wv = tid >> 6;
    int wm = wv >> 1, wn = wv & 1;
    int row0 = blockIdx.y * 128, col0 = blockIdx.x * 128;
    f4v acc[4][4] = {};
    int rsub = tid >> 3;
    int g8 = tid & 7;
    int g8s = g8 ^ (rsub & 7);

    for (int k0 = 0; k0 < 384; k0 += 64) {
        u16x8 ra[4], rb[4];
        #pragma unroll
        for (int c = 0; c < 4; c++) {
            int row = c*32 + rsub;
            ra[c] = *(const u16x8*)(xnb + (size_t)(row0+row)*DCH + k0 + g8*8);
            rb[c] = *(const u16x8*)(Wb  + (size_t)(col0+row)*DCH + k0 + g8*8);
        }
        __syncthreads();
        #pragma unroll
        for (int c = 0; c < 4; c++) {
            int row = c*32 + rsub;
            *(u16x8*)&As[row*64 + g8s*8] = ra[c];
            *(u16x8*)&Bs[row*64 + g8s*8] = rb[c];
        }
        __syncthreads();
        #pragma unroll
        for (int ks = 0; ks < 2; ks++) {
            int gr = (ks*4 + (lane >> 4)) ^ (lane & 7);
            bf8v af[4], bf[4];
            #pragma unroll
            for (int m = 0; m < 4; m++)
                af[m] = *(const bf8v*)&As[(wm*64 + m*16 + (lane & 15))*64 + gr*8];
            #pragma unroll
            for (int n = 0; n < 4; n++)
                bf[n] = *(const bf8v*)&Bs[(wn*64 + n*16 + (lane & 15))*64 + gr*8];
            #pragma unroll
            for (int m = 0; m < 4; m++)
                #pragma unroll
                for (int n = 0; n < 4; n++)
                    acc[m][n] = __builtin_amdgcn_mfma_f32_16x16x32_bf16(af[m], bf[n], acc[m][n], 0, 0, 0);
        }
    }
    int cb = lane & 15, rg = lane >> 4;
    #pragma unroll
    for (int m = 0; m < 4; m++) {
        int r0 = row0 + wm*64 + m*16 + rg*4;
        if (r0 >= ROWS) continue;
        int b = r0 / NTOK, i = r0 - b*NTOK;
        #pragma unroll
        for (int n = 0; n < 4; n++) {
            int ncol = col0 + wn*64 + n*16 + cb;
            int h = ncol / DCH, dc = ncol - h*DCH;
            if (blockIdx.z == 2) {
                size_t addr = ((size_t)((b*DCH + dc)*16 + h))*NTOK + i;
                u16x4 o = {f2b(acc[m][n][0]), f2b(acc[m][n][1]), f2b(acc[m][n][2]), f2b(acc[m][n][3])};
                *(u16x4*)(C + addr) = o;
            } else {
                size_t a2 = ((size_t)(b*DCH + dc))*(NTOK*16) + (size_t)i*16 + h;
                C[a2]      = f2b(acc[m][n][0]);
                C[a2 + 16] = f2b(acc[m][n][1]);
                C[a2 + 32] = f2b(acc[m][n][2]);
                C[a2 + 48] = f2b(acc[m][n][3]);
            }
        }
    }
}

// ------------------------------------------------- MFMA attention v3
// block = bd (448 thr, 7 waves; wave = 32-row i-tile). No max (|s|<~2).
// P kept as packed bf16 (unnormalized) in regs; LDS-transposed coalesced probs
// stores; PV A-frags read straight from the swizzled LDS tile; O scaled by inv at end.
__global__ __launch_bounds__(448) void attn_kernel(
    const u16* __restrict__ qt, const u16* __restrict__ kt, const u16* __restrict__ vt,
    float* __restrict__ probs, u16* __restrict__ ot2)
{
    __shared__ u16 Plds[7][2048];   // per-wave: 32 rows x 64 bf16 (128B row), 16B-chunk swizzle m^(row&7)
    int bd = blockIdx.x;
    int b = bd / DCH, dc = bd - b*DCH;
    int tid = threadIdx.x;
    int it = tid >> 6, lane = tid & 63;
    int l31 = lane & 31, hi = lane >> 5;
    const u16* qb = qt + (size_t)bd * (NTOK*16);
    const u16* kb = kt + (size_t)bd * (NTOK*16);
    const u16* vb = vt + (size_t)bd * (NTOK*16);
    u16* Pw = Plds[it];

    int iq = it*32 + l31;
    int iqc = iq < NTOK ? iq : NTOK-1;
    bf8v qf = *(const bf8v*)(qb + iqc*16 + hi*8);

    unsigned int P[6][8];     // 6 j-tiles x 16 bf16 (unnormalized exp), static-indexed
    float et[4];              // jt=6 tail (valid on hi==0)
    float s0 = 0.f, s1 = 0.f, s2 = 0.f, s3 = 0.f;

    #pragma unroll
    for (int jt = 0; jt < 7; jt++) {
        int j = jt*32 + l31;
        int jc = j < NTOK ? j : NTOK-1;
        bf8v kf = *(const bf8v*)(kb + jc*16 + hi*8);
        f16v z = {};
        f16v Sv = __builtin_amdgcn_mfma_f32_32x32x16_bf16(kf, qf, z, 0, 0, 0);
        if (jt < 6) {
            float e[16];
            #pragma unroll
            for (int r = 0; r < 16; r++) e[r] = __expf(Sv[r] * SCALE);
            #pragma unroll
            for (int r = 0; r < 16; r += 4) {
                s0 += e[r]; s1 += e[r+1]; s2 += e[r+2]; s3 += e[r+3];
            }
            #pragma unroll
            for (int g = 0; g < 4; g++) {
                P[jt][2*g]   = pack2(e[4*g],   e[4*g+1]);
                P[jt][2*g+1] = pack2(e[4*g+2], e[4*g+3]);
            }
        } else {
            #pragma unroll
            for (int r = 0; r < 4; r++)
                et[r] = (hi == 0) ? __expf(Sv[r] * SCALE) : 0.f;
            s0 += et[0]; s1 += et[1]; s2 += et[2]; s3 += et[3];
        }
    }
    float Sig = (s0 + s1) + (s2 + s3);
    Sig += __shfl_xor(Sig, 32);          // combine the row's two halves
    float inv = 1.0f / Sig;              // per-row (row = l31) normalizer

    float* prow_base = probs + (size_t)bd * NTOK * NTOK;
    f16v O = {};
    int row_lo = lane >> 4;      // 0..3 (probs store sublane)
    int scol   = lane & 15;      // 8B-chunk / 4-float column

    #pragma unroll
    for (int jtp = 0; jtp < 3; jtp++) {
        // ---- write this 64-j slab into the swizzled LDS tile (raw packed bf16)
        #pragma unroll
        for (int jtl = 0; jtl < 2; jtl++) {
            int jt = jtp*2 + jtl;
            #pragma unroll
            for (int g = 0; g < 4; g++) {
                int cs  = jtl*8 + 2*g + hi;              // 8B chunk 0..15
                int csw = cs ^ ((l31 & 7) << 1);         // even-mask XOR keeps 16B pairing
                u32x2 w2 = {P[jt][2*g], P[jt][2*g+1]};
                *(u32x2*)&Pw[l31*64 + csw*4] = w2;
            }
        }
        // ---- coalesced probs stores: 4 rows x 64 consecutive floats per instr
        #pragma unroll
        for (int rr = 0; rr < 8; rr++) {
            int row = rr*4 + row_lo;
            float rinv = __shfl(inv, row);               // all lanes active here
            int csw = scol ^ ((row & 7) << 1);
            u32x2 pv = *(const u32x2*)&Pw[row*64 + csw*4];
            int gi = it*32 + row;
            if (gi < NTOK) {
                f4v o = {blo(pv.x)*rinv, bhi(pv.x)*rinv, blo(pv.y)*rinv, bhi(pv.y)*rinv};
                *(f4v*)(prow_base + (size_t)gi*NTOK + jtp*64 + scol*4) = o;
            }
        }
        // ---- PV: A-frag = straight b128 read from the tile (row=l31, 8 consecutive j)
        #pragma unroll
        for (int jtl = 0; jtl < 2; jtl++) {
            #pragma unroll
            for (int u = 0; u < 2; u++) {
                int m  = jtl*4 + u*2 + hi;               // 16B chunk 0..7
                int mw = m ^ (l31 & 7);
                bf8v pf = *(const bf8v*)&Pw[l31*64 + mw*8];
                int j0 = jtp*64 + jtl*32 + u*16 + hi*8;
                int off = (l31 & 15)*NTOK + j0;
                u16x4 vlo = *(const u16x4*)(vb + off);
                u16x4 vh4 = *(const u16x4*)(vb + off + 4);
                u16 varr[8];
                #pragma unroll
                for (int e = 0; e < 4; e++) { varr[e] = vlo[e]; varr[4+e] = vh4[e]; }
                bf8v vf; __builtin_memcpy(&vf, varr, 16);
                O = __builtin_amdgcn_mfma_f32_32x32x16_bf16(pf, vf, O, 0, 0, 0);
            }
        }
    }

    // ---- tail jt=6 (j 192..195): probs + PV (frag is lane-local, no shfl)
    if (hi == 0 && iq < NTOK) {
        f4v o = {et[0]*inv, et[1]*inv, et[2]*inv, et[3]*inv};
        *(f4v*)(prow_base + (size_t)iq*NTOK + 192) = o;
    }
    {
        u16 arr[8];
        #pragma unroll
        for (int e = 0; e < 4; e++) {
            arr[e]   = (hi == 0) ? f2b(et[e]) : (u16)0;
            arr[4+e] = 0;
        }
        bf8v pf; __builtin_memcpy(&pf, arr, 16);
        int j0 = 192 + hi*8;
        int off = (l31 & 15)*NTOK + j0;    // may read a few u16 past this bd's v (x0 elems) — benign
        u16x4 vlo = *(const u16x4*)(vb + off);
        u16x4 vh4 = *(const u16x4*)(vb + off + 4);
        u16 varr[8];
        #pragma unroll
        for (int e = 0; e < 4; e++) { varr[e] = vlo[e]; varr[4+e] = vh4[e]; }
        bf8v vf; __builtin_memcpy(&vf, varr, 16);
        O = __builtin_amdgcn_mfma_f32_32x32x16_bf16(pf, vf, O, 0, 0, 0);
    }

    // ---- scale O by each row's inv (shfl BEFORE the store guard: all lanes active)
    float sc[16];
    #pragma unroll
    for (int r = 0; r < 16; r++) {
        int il = (r & 3) + 8*(r >> 2) + 4*hi;
        sc[r] = __shfl(inv, il);
    }
    if (l31 < 16) {
        #pragma unroll
        for (int r = 0; r < 16; r++) {
            int i = it*32 + (r & 3) + 8*(r >> 2) + 4*hi;
            if (i < NTOK)
                ot2[((size_t)(b*NTOK + i))*HD + dc*16 + l31] = f2b(O[r] * sc[r]);
        }
    }
}

// ------------------------------------------------- MFMA out-proj (reg-staged), split-K
__global__ __launch_bounds__(256) void gemm_wout(
    const u16* __restrict__ A, const u16* __restrict__ Bw, float* __restrict__ partial)
{
    __shared__ u16 As[128*64];
    __shared__ u16 Bs[128*64];
    int tid = threadIdx.x, lane = tid & 63, wv = tid >> 6;
    int wm = wv >> 1, wn = wv & 1;
    int row0 = blockIdx.y * 128, col0 = blockIdx.x * 128;
    int kbase = blockIdx.z * 512;
    f4v acc[4][4] = {};
    int rsub = tid >> 3;
    int g8 = tid & 7;
    int g8s = g8 ^ (rsub & 7);

    for (int k0 = kbase; k0 < kbase + 512; k0 += 64) {
        u16x8 ra[4], rb[4];
        #pragma unroll
        for (int c = 0; c < 4; c++) {
            int row = c*32 + rsub;
            int arow = row0 + row; if (arow > ROWS-1) arow = ROWS-1;   // clamp (masked at store)
            ra[c] = *(const u16x8*)(A  + (size_t)arow*HD + k0 + g8*8);
            rb[c] = *(const u16x8*)(Bw + (size_t)(col0+row)*HD + k0 + g8*8);
        }
        __syncthreads();
        #pragma unroll
        for (int c = 0; c < 4; c++) {
            int row = c*32 + rsub;
            *(u16x8*)&As[row*64 + g8s*8] = ra[c];
            *(u16x8*)&Bs[row*64 + g8s*8] = rb[c];
        }
        __syncthreads();
        #pragma unroll
        for (int ks = 0; ks < 2; ks++) {
            int gr = (ks*4 + (lane >> 4)) ^ (lane & 7);
            bf8v af[4], bf[4];
            #pragma unroll
            for (int m = 0; m < 4; m++)
                af[m] = *(const bf8v*)&As[(wm*64 + m*16 + (lane & 15))*64 + gr*8];
            #pragma unroll
            for (int n = 0; n < 4; n++)
                bf[n] = *(const bf8v*)&Bs[(wn*64 + n*16 + (lane & 15))*64 + gr*8];
            #pragma unroll
            for (int m = 0; m < 4; m++)
                #pragma unroll
                for (int n = 0; n < 4; n++)
                    acc[m][n] = __builtin_amdgcn_mfma_f32_16x16x32_bf16(af[m], bf[n], acc[m][n], 0, 0, 0);
        }
    }
    float* Pp = partial + (size_t)blockIdx.z * ROWS * DCH;
    int cb = lane & 15, rg = lane >> 4;
    #pragma unroll
    for (int m = 0; m < 4; m++) {
        int r0 = row0 + wm*64 + m*16 + rg*4;
        #pragma unroll
        for (int n = 0; n < 4; n++) {
            int ncol = col0 + wn*64 + n*16 + cb;
            #pragma unroll
            for (int j = 0; j < 4; j++) {
                int r = r0 + j;
                if (r < ROWS) Pp[(size_t)r*DCH + ncol] = acc[m][n][j];
            }
        }
    }
}

// ------------------------------------------------- split-K reduce + residual
__global__ __launch_bounds__(256) void reduce_out_kernel(
    const float* __restrict__ partial, const float* __restrict__ xn, float* __restrict__ out)
{
    int e = blockIdx.x * 256 + threadIdx.x;
    if (e < ROWS * DCH) {
        float s = xn[e];
        #pragma unroll
        for (int c = 0; c < 12; c++)
            s += partial[(size_t)c * ROWS * DCH + e];
        out[e] = s;
    }
}

extern "C" void kernel_launch(void* const* d_in, const int* in_sizes, int n_in,
                              void* d_out, int out_size, void* d_ws, size_t ws_size,
                              hipStream_t stream) {
    (void)in_sizes; (void)n_in; (void)out_size; (void)ws_size;
    const float* x     = (const float*)d_in[0];
    const float* Wq    = (const float*)d_in[1];
    const float* Wk    = (const float*)d_in[2];
    const float* Wv    = (const float*)d_in[3];
    const float* Wout  = (const float*)d_in[4];
    const float* gamma = (const float*)d_in[5];
    const float* beta  = (const float*)d_in[6];

    float* out   = (float*)d_out;
    float* probs = out + (size_t)ROWS * DCH;

    char* w = (char*)d_ws;
    float* xn  = (float*)w;  w += (size_t)ROWS*DCH*4;
    u16* xnb   = (u16*)w;    w += (size_t)MPAD*DCH*2;
    u16* Wqb   = (u16*)w;    w += (size_t)HD*DCH*2;
    u16* Wkb   = (u16*)w;    w += (size_t)HD*DCH*2;
    u16* Wvb   = (u16*)w;    w += (size_t)HD*DCH*2;
    u16* Woutb = (u16*)w;    w += (size_t)DCH*HD*2;
    u16* qt    = (u16*)w;    w += (size_t)ROWS*HD*2;
    u16* kt    = (u16*)w;    w += (size_t)ROWS*HD*2;
    u16* vt    = (u16*)w;    w += (size_t)ROWS*HD*2;
    u16* ot2   = (u16*)w;    w += (size_t)ROWS*HD*2;
    float* partial = (float*)qt;   // q/k dead after attention

    hipLaunchKernelGGL(ln_kernel, dim3(MPAD), dim3(128), 0, stream, x, gamma, beta, xn, xnb);
    hipLaunchKernelGGL(convert_w_kernel, dim3(192, 12, 3), dim3(256), 0, stream,
                       Wq, Wk, Wv, Wqb, Wkb, Wvb);
    hipLaunchKernelGGL(convert_wout_kernel, dim3(48, 6), dim3(256), 0, stream, Wout, Woutb);
    hipLaunchKernelGGL(gemm_qkv, dim3(48, 7, 3), dim3(256), 0, stream,
                       xnb, Wqb, Wkb, Wvb, qt, kt, vt);
    hipLaunchKernelGGL(attn_kernel, dim3(BS * DCH), dim3(448), 0, stream,
                       qt, kt, vt, probs, ot2);
    hipLaunchKernelGGL(gemm_wout, dim3(3, 7, 12), dim3(256), 0, stream, ot2, Woutb, partial);
    hipLaunchKernelGGL(reduce_out_kernel, dim3((ROWS * DCH + 255) / 256), dim3(256), 0, stream,
                       partial, xn, out);
}